// Round 1
// baseline (848.323 us; speedup 1.0000x reference)
//
#include <hip/hip_runtime.h>
#include <hip/hip_bf16.h>

// Problem constants
#define BB 8
#define SS 4096
#define DD 1024
#define HH 16
#define LL 6
#define FF 2048
#define VV 256
#define NC 16   // ctx s-chunks

// Workspace layout (float offsets)
#define OFF_PE   0L
#define OFF_SC   (OFF_PE + (long)SS*DD)          // B*H*S scores
#define OFF_U    (OFF_SC + (long)BB*HH*SS)       // B*H*D
#define OFF_CTXP (OFF_U + (long)BB*HH*DD)        // NC*B*H*D
#define OFF_CTX  (OFF_CTXP + (long)NC*BB*HH*DD)  // B*H*D
#define OFF_Q    (OFF_CTX + (long)BB*HH*DD)      // B*D
#define OFF_O    (OFF_Q + (long)BB*DD)           // B*D
#define OFF_X0   (OFF_O + (long)BB*DD)           // B*D
#define OFF_V    (OFF_X0 + (long)BB*DD)          // B*D
#define OFF_O2   (OFF_V + (long)BB*DD)           // B*D
#define OFF_Y    (OFF_O2 + (long)BB*DD)          // B*D
#define OFF_H    (OFF_Y + (long)BB*DD)           // B*F
#define OFF_Z    (OFF_H + (long)BB*FF)           // B*D

// ---------------- positional encoding: pe[s, 2i]=sin(s*div_i), pe[s,2i+1]=cos ----------------
__global__ __launch_bounds__(256) void pe_kernel(float* __restrict__ pe) {
    int s = blockIdx.x;
    float fs = (float)s;
    for (int i = threadIdx.x; i < DD / 2; i += 256) {
        float div = expf((-logf(10000.0f) / (float)DD) * (float)(2 * i));
        float a = fs * div;
        pe[(long)s * DD + 2 * i]     = sinf(a);
        pe[(long)s * DD + 2 * i + 1] = cosf(a);
    }
}

// ---------------- generic small GEMM: C[m,n] = act( sum_k (A[m,k]+A2[m,k]) * W[n,k] + bias[n] + R1[m,n] + R2[m,n] )
// M is fixed at 8. One wave per output column n.
__global__ __launch_bounds__(256) void gemm8(
    const float* __restrict__ A, long sA,
    const float* __restrict__ A2, long sA2,
    const float* __restrict__ W,
    const float* __restrict__ bias,
    const float* __restrict__ R1, long sR1,
    const float* __restrict__ R2, long sR2,
    float* __restrict__ C, int N, int K, int relu)
{
    int wave = threadIdx.x >> 6, lane = threadIdx.x & 63;
    int n = blockIdx.x * 4 + wave;
    if (n >= N) return;
    float acc[8] = {0.f,0.f,0.f,0.f,0.f,0.f,0.f,0.f};
    const float4* W4 = reinterpret_cast<const float4*>(W + (long)n * K);
    for (int kb = 0; kb < K; kb += 256) {
        int k4 = (kb >> 2) + lane;
        float4 w = W4[k4];
        #pragma unroll
        for (int m = 0; m < 8; ++m) {
            float4 a = reinterpret_cast<const float4*>(A + (long)m * sA)[k4];
            if (A2) {
                float4 a2 = reinterpret_cast<const float4*>(A2 + (long)m * sA2)[k4];
                a.x += a2.x; a.y += a2.y; a.z += a2.z; a.w += a2.w;
            }
            acc[m] += a.x * w.x + a.y * w.y + a.z * w.z + a.w * w.w;
        }
    }
    #pragma unroll
    for (int m = 0; m < 8; ++m)
        for (int off = 32; off; off >>= 1) acc[m] += __shfl_xor(acc[m], off, 64);
    if (lane == 0) {
        float bs = bias ? bias[n] : 0.f;
        #pragma unroll
        for (int m = 0; m < 8; ++m) {
            float v = acc[m] + bs;
            if (R1) v += R1[(long)m * sR1 + n];
            if (R2) v += R2[(long)m * sR2 + n];
            if (relu) v = fmaxf(v, 0.f);
            C[(long)m * N + n] = v;
        }
    }
}

// ---------------- LayerNorm over last dim for 8 rows ----------------
__global__ __launch_bounds__(256) void ln8(const float* __restrict__ x,
                                           const float* __restrict__ w,
                                           const float* __restrict__ b,
                                           float* __restrict__ o, int N)
{
    int m = blockIdx.x, t = threadIdx.x;
    const float* xr = x + (long)m * N;
    float s1 = 0.f, s2 = 0.f;
    for (int k = t; k < N; k += 256) { float v = xr[k]; s1 += v; s2 += v * v; }
    __shared__ float r1[4], r2[4];
    for (int off = 32; off; off >>= 1) { s1 += __shfl_xor(s1, off, 64); s2 += __shfl_xor(s2, off, 64); }
    if ((t & 63) == 0) { r1[t >> 6] = s1; r2[t >> 6] = s2; }
    __syncthreads();
    s1 = r1[0] + r1[1] + r1[2] + r1[3];
    s2 = r2[0] + r2[1] + r2[2] + r2[3];
    float mean = s1 / (float)N;
    float var  = s2 / (float)N - mean * mean;
    float rstd = rsqrtf(var + 1e-5f);
    for (int k = t; k < N; k += 256)
        o[(long)m * N + k] = (xr[k] - mean) * rstd * w[k] + b[k];
}

// ---------------- u[b,h,:] = sum_d Q[b, h*64+d] * wk[h*64+d, :] ----------------
__global__ __launch_bounds__(256) void u_kernel(const float* __restrict__ Q,
                                                const float* __restrict__ wk,
                                                float* __restrict__ u)
{
    int h = blockIdx.y;
    int e = blockIdx.x * 256 + threadIdx.x;
    __shared__ float qs[8][64];
    for (int idx = threadIdx.x; idx < 512; idx += 256) {
        int b = idx >> 6, d = idx & 63;
        qs[b][d] = Q[(long)b * DD + h * 64 + d];
    }
    __syncthreads();
    float acc[8] = {0.f,0.f,0.f,0.f,0.f,0.f,0.f,0.f};
    for (int d = 0; d < 64; ++d) {
        float wv = wk[(long)(h * 64 + d) * DD + e];
        #pragma unroll
        for (int b = 0; b < 8; ++b) acc[b] += qs[b][d] * wv;
    }
    #pragma unroll
    for (int b = 0; b < 8; ++b) u[((long)(b * HH + h)) * DD + e] = acc[b];
}

// ---------------- sc[b,h,s] = 0.125 * dot(u[b,h,:], tgt[b,s,:]+pe[s,:]) ----------------
__global__ __launch_bounds__(256) void score_kernel(const float* __restrict__ tgt,
                                                    const float* __restrict__ pe,
                                                    const float* __restrict__ u,
                                                    float* __restrict__ sc)
{
    int b = blockIdx.y;
    int s0 = blockIdx.x * 32;
    __shared__ float us[16 * 1024];
    const float4* ub4 = reinterpret_cast<const float4*>(u + (long)b * HH * DD);
    float4* us4 = reinterpret_cast<float4*>(us);
    for (int idx = threadIdx.x; idx < HH * DD / 4; idx += 256) us4[idx] = ub4[idx];
    __syncthreads();
    int wave = threadIdx.x >> 6, lane = threadIdx.x & 63;
    for (int grp = 0; grp < 2; ++grp) {
        int sbase = s0 + wave * 8 + grp * 4;
        float acc[16][4];
        #pragma unroll
        for (int h = 0; h < 16; ++h)
            #pragma unroll
            for (int r = 0; r < 4; ++r) acc[h][r] = 0.f;
        for (int kb = 0; kb < DD; kb += 256) {
            int j = (kb >> 2) + lane;
            float4 x[4];
            #pragma unroll
            for (int r = 0; r < 4; ++r) {
                float4 tv = reinterpret_cast<const float4*>(tgt + ((long)b * SS + sbase + r) * DD)[j];
                float4 pv = reinterpret_cast<const float4*>(pe + (long)(sbase + r) * DD)[j];
                x[r] = make_float4(tv.x + pv.x, tv.y + pv.y, tv.z + pv.z, tv.w + pv.w);
            }
            #pragma unroll
            for (int h = 0; h < 16; ++h) {
                float4 uv = us4[h * (DD / 4) + j];
                #pragma unroll
                for (int r = 0; r < 4; ++r)
                    acc[h][r] += uv.x * x[r].x + uv.y * x[r].y + uv.z * x[r].z + uv.w * x[r].w;
            }
        }
        #pragma unroll
        for (int h = 0; h < 16; ++h)
            #pragma unroll
            for (int r = 0; r < 4; ++r) {
                float v = acc[h][r];
                for (int off = 32; off; off >>= 1) v += __shfl_xor(v, off, 64);
                if (lane == 0) sc[((long)(b * HH + h)) * SS + sbase + r] = v * 0.125f;
            }
    }
}

// ---------------- in-place softmax over 4096 per (b,h) row ----------------
__global__ __launch_bounds__(256) void softmax_kernel(float* __restrict__ sc)
{
    int row = blockIdx.x;
    float* p = sc + (long)row * SS;
    int t = threadIdx.x;
    float4 v[4];
    float mx = -1e30f;
    const float4* p4 = reinterpret_cast<const float4*>(p);
    #pragma unroll
    for (int i = 0; i < 4; ++i) {
        v[i] = p4[t + 256 * i];
        mx = fmaxf(mx, fmaxf(fmaxf(v[i].x, v[i].y), fmaxf(v[i].z, v[i].w)));
    }
    __shared__ float red[4];
    for (int off = 32; off; off >>= 1) mx = fmaxf(mx, __shfl_xor(mx, off, 64));
    if ((t & 63) == 0) red[t >> 6] = mx;
    __syncthreads();
    mx = fmaxf(fmaxf(red[0], red[1]), fmaxf(red[2], red[3]));
    __syncthreads();
    float sum = 0.f;
    #pragma unroll
    for (int i = 0; i < 4; ++i) {
        v[i].x = expf(v[i].x - mx); v[i].y = expf(v[i].y - mx);
        v[i].z = expf(v[i].z - mx); v[i].w = expf(v[i].w - mx);
        sum += v[i].x + v[i].y + v[i].z + v[i].w;
    }
    for (int off = 32; off; off >>= 1) sum += __shfl_xor(sum, off, 64);
    if ((t & 63) == 0) red[t >> 6] = sum;
    __syncthreads();
    sum = red[0] + red[1] + red[2] + red[3];
    float inv = 1.f / sum;
    float4* p4w = reinterpret_cast<float4*>(p);
    #pragma unroll
    for (int i = 0; i < 4; ++i) {
        v[i].x *= inv; v[i].y *= inv; v[i].z *= inv; v[i].w *= inv;
        p4w[t + 256 * i] = v[i];
    }
}

// ---------------- ctx partials: ctxp[c,b,h,e] = sum_{s in chunk c} p[b,h,s]*(tgt[b,s,e]+pe[s,e]) ----------------
__global__ __launch_bounds__(256) void ctxp_kernel(const float* __restrict__ tgt,
                                                   const float* __restrict__ pe,
                                                   const float* __restrict__ p,
                                                   float* __restrict__ ctxp)
{
    int c = blockIdx.x;   // s-chunk
    int ec = blockIdx.y;  // e-chunk
    int b = blockIdx.z;
    int e = ec * 256 + threadIdx.x;
    int s0 = c * (SS / NC);
    __shared__ float ps[16][256];
    for (int idx = threadIdx.x; idx < 16 * 256; idx += 256) {
        int h = idx >> 8, j = idx & 255;
        ps[h][j] = p[((long)(b * HH + h)) * SS + s0 + j];
    }
    __syncthreads();
    float acc[16];
    #pragma unroll
    for (int h = 0; h < 16; ++h) acc[h] = 0.f;
    for (int sj = 0; sj < SS / NC; sj += 4) {
        float x[4];
        #pragma unroll
        for (int r = 0; r < 4; ++r)
            x[r] = tgt[((long)b * SS + s0 + sj + r) * DD + e] + pe[(long)(s0 + sj + r) * DD + e];
        #pragma unroll
        for (int h = 0; h < 16; ++h) {
            float4 pv = *reinterpret_cast<const float4*>(&ps[h][sj]);
            acc[h] += pv.x * x[0] + pv.y * x[1] + pv.z * x[2] + pv.w * x[3];
        }
    }
    #pragma unroll
    for (int h = 0; h < 16; ++h)
        ctxp[(((long)c * BB + b) * HH + h) * DD + e] = acc[h];
}

__global__ __launch_bounds__(256) void ctxred_kernel(const float* __restrict__ ctxp,
                                                     float* __restrict__ ctx)
{
    long i = (long)blockIdx.x * 256 + threadIdx.x;
    float s = 0.f;
    for (int c = 0; c < NC; ++c) s += ctxp[(long)c * BB * HH * DD + i];
    ctx[i] = s;
}

// ---------------- o[b, j] = sum_e wv[j,e]*ctx[b, j>>6, e] + bv[j] ----------------
__global__ __launch_bounds__(256) void ov_kernel(const float* __restrict__ ctx,
                                                 const float* __restrict__ wv,
                                                 const float* __restrict__ bv,
                                                 float* __restrict__ o)
{
    int wave = threadIdx.x >> 6, lane = threadIdx.x & 63;
    int j = blockIdx.x * 4 + wave;
    if (j >= DD) return;
    int h = j >> 6;
    float acc[8] = {0.f,0.f,0.f,0.f,0.f,0.f,0.f,0.f};
    const float4* w4 = reinterpret_cast<const float4*>(wv + (long)j * DD);
    for (int kb = 0; kb < DD; kb += 256) {
        int k4 = (kb >> 2) + lane;
        float4 w = w4[k4];
        #pragma unroll
        for (int b = 0; b < 8; ++b) {
            float4 a = reinterpret_cast<const float4*>(ctx + ((long)(b * HH + h)) * DD)[k4];
            acc[b] += a.x * w.x + a.y * w.y + a.z * w.z + a.w * w.w;
        }
    }
    #pragma unroll
    for (int b = 0; b < 8; ++b)
        for (int off = 32; off; off >>= 1) acc[b] += __shfl_xor(acc[b], off, 64);
    if (lane == 0) {
        float bs = bv[j];
        #pragma unroll
        for (int b = 0; b < 8; ++b) o[(long)b * DD + j] = acc[b] + bs;
    }
}

extern "C" void kernel_launch(void* const* d_in, const int* in_sizes, int n_in,
                              void* d_out, int out_size, void* d_ws, size_t ws_size,
                              hipStream_t stream)
{
    const float* tgt        = (const float*)d_in[0];
    const float* in_proj_w  = (const float*)d_in[1];
    const float* in_proj_b  = (const float*)d_in[2];
    const float* out_proj_w = (const float*)d_in[3];
    const float* out_proj_b = (const float*)d_in[4];
    const float* ln1_w      = (const float*)d_in[5];
    const float* ln1_b      = (const float*)d_in[6];
    const float* lin1_w     = (const float*)d_in[7];
    const float* lin1_b     = (const float*)d_in[8];
    const float* lin2_w     = (const float*)d_in[9];
    const float* lin2_b     = (const float*)d_in[10];
    const float* ln2_w      = (const float*)d_in[11];
    const float* ln2_b      = (const float*)d_in[12];
    const float* w_out      = (const float*)d_in[13];
    const float* b_out      = (const float*)d_in[14];

    float* ws   = (float*)d_ws;
    float* pe   = ws + OFF_PE;
    float* sc   = ws + OFF_SC;
    float* u    = ws + OFF_U;
    float* ctxp = ws + OFF_CTXP;
    float* ctx  = ws + OFF_CTX;
    float* Q    = ws + OFF_Q;
    float* o    = ws + OFF_O;
    float* x0   = ws + OFF_X0;
    float* vb   = ws + OFF_V;
    float* o2   = ws + OFF_O2;
    float* y    = ws + OFF_Y;
    float* hb   = ws + OFF_H;
    float* z    = ws + OFF_Z;

    const float* tgt_last = tgt + (long)(SS - 1) * DD;
    const float* pe_last  = pe + (long)(SS - 1) * DD;

    // 1. positional encoding table
    pe_kernel<<<SS, 256, 0, stream>>>(pe);

    // 2. Q = (tgt_last + pe_last) @ wq0^T + bq0
    gemm8<<<DD / 4, 256, 0, stream>>>(tgt_last, (long)SS * DD, pe_last, 0L,
                                      in_proj_w, in_proj_b,
                                      nullptr, 0L, nullptr, 0L, Q, DD, DD, 0);

    // 3. u[b,h,:] = sum_d Q[b,h,d] * wk0[h*64+d,:]   (bk dropped: softmax-invariant)
    u_kernel<<<dim3(4, 16), 256, 0, stream>>>(Q, in_proj_w + (long)DD * DD, u);

    // 4. scores, 5. softmax, 6. ctx
    score_kernel<<<dim3(SS / 32, BB), 256, 0, stream>>>(tgt, pe, u, sc);
    softmax_kernel<<<BB * HH, 256, 0, stream>>>(sc);
    ctxp_kernel<<<dim3(NC, 4, BB), 256, 0, stream>>>(tgt, pe, sc, ctxp);
    ctxred_kernel<<<(BB * HH * DD) / 256, 256, 0, stream>>>(ctxp, ctx);

    // 7. o[b,:] = wv0 @ ctx + bv0   (sum a = 1 passes bias through)
    ov_kernel<<<DD / 4, 256, 0, stream>>>(ctx, in_proj_w + 2L * DD * DD, in_proj_b + 2 * DD, o);

    // 8. layer-0 tail: o2 = (tgt_last+pe_last) + o @ wo0^T + bo0
    gemm8<<<DD / 4, 256, 0, stream>>>(o, (long)DD, nullptr, 0L,
                                      out_proj_w, out_proj_b,
                                      tgt_last, (long)SS * DD, pe_last, 0L, o2, DD, DD, 0);
    ln8<<<BB, 256, 0, stream>>>(o2, ln1_w, ln1_b, y, DD);
    gemm8<<<FF / 4, 256, 0, stream>>>(y, (long)DD, nullptr, 0L,
                                      lin1_w, lin1_b,
                                      nullptr, 0L, nullptr, 0L, hb, FF, DD, 1);
    gemm8<<<DD / 4, 256, 0, stream>>>(hb, (long)FF, nullptr, 0L,
                                      lin2_w, lin2_b,
                                      y, (long)DD, nullptr, 0L, z, DD, FF, 0);
    ln8<<<BB, 256, 0, stream>>>(z, ln2_w, ln2_b, x0, DD);

    // 9. layers 1..5: seq len 1 -> softmax(1)=1 -> attn out = x0 @ wv^T + bv
    for (int i = 1; i < LL; ++i) {
        const float* wv_i = in_proj_w + (long)i * 3 * DD * DD + 2L * DD * DD;
        const float* bv_i = in_proj_b + (long)i * 3 * DD + 2 * DD;
        gemm8<<<DD / 4, 256, 0, stream>>>(x0, (long)DD, nullptr, 0L,
                                          wv_i, bv_i, nullptr, 0L, nullptr, 0L, vb, DD, DD, 0);
        gemm8<<<DD / 4, 256, 0, stream>>>(vb, (long)DD, nullptr, 0L,
                                          out_proj_w + (long)i * DD * DD, out_proj_b + (long)i * DD,
                                          x0, (long)DD, nullptr, 0L, o2, DD, DD, 0);
        ln8<<<BB, 256, 0, stream>>>(o2, ln1_w + (long)i * DD, ln1_b + (long)i * DD, y, DD);
        gemm8<<<FF / 4, 256, 0, stream>>>(y, (long)DD, nullptr, 0L,
                                          lin1_w + (long)i * FF * DD, lin1_b + (long)i * FF,
                                          nullptr, 0L, nullptr, 0L, hb, FF, DD, 1);
        gemm8<<<DD / 4, 256, 0, stream>>>(hb, (long)FF, nullptr, 0L,
                                          lin2_w + (long)i * DD * FF, lin2_b + (long)i * DD,
                                          y, (long)DD, nullptr, 0L, z, DD, FF, 0);
        ln8<<<BB, 256, 0, stream>>>(z, ln2_w + (long)i * DD, ln2_b + (long)i * DD, x0, DD);
    }

    // 10. final: out = x0 @ w_out^T + b_out  -> (B, 256)
    gemm8<<<VV / 4, 256, 0, stream>>>(x0, (long)DD, nullptr, 0L,
                                      w_out, b_out,
                                      nullptr, 0L, nullptr, 0L, (float*)d_out, VV, DD, 0);
}

// Round 2
// 831.805 us; speedup vs baseline: 1.0199x; 1.0199x over previous
//
#include <hip/hip_runtime.h>
#include <hip/hip_bf16.h>

// Problem constants
#define BB 8
#define SS 4096
#define DD 1024
#define HH 16
#define LL 6
#define FF 2048
#define VV 256
#define EH 512        // e-half size for score pass
#define CTX_SC 64     // ctx pass s-chunks (s-chunk size = SS/CTX_SC = 64)

// Workspace layout (float offsets). Total ~6.1M floats (~24.4 MB).
#define OFF_PE   0L
#define OFF_SCP  (OFF_PE + (long)SS*DD)            // 2 * B*H*S partial scores
#define OFF_SC   (OFF_SCP + 2L*BB*HH*SS)           // B*H*S probabilities
#define OFF_U    (OFF_SC + (long)BB*HH*SS)         // B*H*D
#define OFF_CTX  (OFF_U + (long)BB*HH*DD)          // B*H*D
#define OFF_Q    (OFF_CTX + (long)BB*HH*DD)        // B*D
#define OFF_O    (OFF_Q + (long)BB*DD)             // B*D
#define OFF_X0   (OFF_O + (long)BB*DD)             // B*D
#define OFF_V    (OFF_X0 + (long)BB*DD)            // B*D
#define OFF_O2   (OFF_V + (long)BB*DD)             // B*D
#define OFF_Y    (OFF_O2 + (long)BB*DD)            // B*D
#define OFF_H    (OFF_Y + (long)BB*DD)             // B*F
#define OFF_Z    (OFF_H + (long)BB*FF)             // B*D

// ---------------- positional encoding ----------------
__global__ __launch_bounds__(256) void pe_kernel(float* __restrict__ pe) {
    int s = blockIdx.x;
    float fs = (float)s;
    for (int i = threadIdx.x; i < DD / 2; i += 256) {
        float div = expf((-logf(10000.0f) / (float)DD) * (float)(2 * i));
        float a = fs * div;
        pe[(long)s * DD + 2 * i]     = sinf(a);
        pe[(long)s * DD + 2 * i + 1] = cosf(a);
    }
}

// ---------------- generic small GEMM (M=8), one wave per output column ----------------
__global__ __launch_bounds__(256) void gemm8(
    const float* __restrict__ A, long sA,
    const float* __restrict__ A2, long sA2,
    const float* __restrict__ W,
    const float* __restrict__ bias,
    const float* __restrict__ R1, long sR1,
    const float* __restrict__ R2, long sR2,
    float* __restrict__ C, int N, int K, int relu)
{
    int wave = threadIdx.x >> 6, lane = threadIdx.x & 63;
    int n = blockIdx.x * 4 + wave;
    if (n >= N) return;
    float acc[8] = {0.f,0.f,0.f,0.f,0.f,0.f,0.f,0.f};
    const float4* W4 = reinterpret_cast<const float4*>(W + (long)n * K);
    for (int kb = 0; kb < K; kb += 256) {
        int k4 = (kb >> 2) + lane;
        float4 w = W4[k4];
        #pragma unroll
        for (int m = 0; m < 8; ++m) {
            float4 a = reinterpret_cast<const float4*>(A + (long)m * sA)[k4];
            if (A2) {
                float4 a2 = reinterpret_cast<const float4*>(A2 + (long)m * sA2)[k4];
                a.x += a2.x; a.y += a2.y; a.z += a2.z; a.w += a2.w;
            }
            acc[m] += a.x * w.x + a.y * w.y + a.z * w.z + a.w * w.w;
        }
    }
    #pragma unroll
    for (int m = 0; m < 8; ++m)
        for (int off = 32; off; off >>= 1) acc[m] += __shfl_xor(acc[m], off, 64);
    if (lane == 0) {
        float bs = bias ? bias[n] : 0.f;
        #pragma unroll
        for (int m = 0; m < 8; ++m) {
            float v = acc[m] + bs;
            if (R1) v += R1[(long)m * sR1 + n];
            if (R2) v += R2[(long)m * sR2 + n];
            if (relu) v = fmaxf(v, 0.f);
            C[(long)m * N + n] = v;
        }
    }
}

// ---------------- LayerNorm over last dim for 8 rows ----------------
__global__ __launch_bounds__(256) void ln8(const float* __restrict__ x,
                                           const float* __restrict__ w,
                                           const float* __restrict__ b,
                                           float* __restrict__ o, int N)
{
    int m = blockIdx.x, t = threadIdx.x;
    const float* xr = x + (long)m * N;
    float s1 = 0.f, s2 = 0.f;
    for (int k = t; k < N; k += 256) { float v = xr[k]; s1 += v; s2 += v * v; }
    __shared__ float r1[4], r2[4];
    for (int off = 32; off; off >>= 1) { s1 += __shfl_xor(s1, off, 64); s2 += __shfl_xor(s2, off, 64); }
    if ((t & 63) == 0) { r1[t >> 6] = s1; r2[t >> 6] = s2; }
    __syncthreads();
    s1 = r1[0] + r1[1] + r1[2] + r1[3];
    s2 = r2[0] + r2[1] + r2[2] + r2[3];
    float mean = s1 / (float)N;
    float var  = s2 / (float)N - mean * mean;
    float rstd = rsqrtf(var + 1e-5f);
    for (int k = t; k < N; k += 256)
        o[(long)m * N + k] = (xr[k] - mean) * rstd * w[k] + b[k];
}

// ---------------- u[b,h,:] = sum_d Q[b, h*64+d] * wk[h*64+d, :] ----------------
__global__ __launch_bounds__(256) void u_kernel(const float* __restrict__ Q,
                                                const float* __restrict__ wk,
                                                float* __restrict__ u)
{
    int h = blockIdx.y;
    int e = blockIdx.x * 256 + threadIdx.x;
    __shared__ float qs[8][64];
    for (int idx = threadIdx.x; idx < 512; idx += 256) {
        int b = idx >> 6, d = idx & 63;
        qs[b][d] = Q[(long)b * DD + h * 64 + d];
    }
    __syncthreads();
    float acc[8] = {0.f,0.f,0.f,0.f,0.f,0.f,0.f,0.f};
    for (int d = 0; d < 64; ++d) {
        float wv = wk[(long)(h * 64 + d) * DD + e];
        #pragma unroll
        for (int b = 0; b < 8; ++b) acc[b] += qs[b][d] * wv;
    }
    #pragma unroll
    for (int b = 0; b < 8; ++b) u[((long)(b * HH + h)) * DD + e] = acc[b];
}

// ---------------- score partial: scp[eh][b*H+h][s] = dot(u[b,h,eh-half], x[b,s,eh-half]) ----------------
// grid (SS/32, 2, BB), block 256. LDS 32 KB u-tile. acc[16][2] per lane -> low VGPR.
__global__ __launch_bounds__(256) void score2_kernel(const float* __restrict__ tgt,
                                                     const float* __restrict__ pe,
                                                     const float* __restrict__ u,
                                                     float* __restrict__ scp)
{
    int b = blockIdx.z, eh = blockIdx.y;
    int s0 = blockIdx.x * 32;
    __shared__ float us[16 * EH];   // 32 KB
    float4* us4 = reinterpret_cast<float4*>(us);
    const float* ub = u + (long)b * HH * DD + eh * EH;
    for (int idx = threadIdx.x; idx < 16 * EH / 4; idx += 256) {
        int h = idx >> 7, j = idx & 127;   // EH/4 = 128
        us4[idx] = reinterpret_cast<const float4*>(ub + (long)h * DD)[j];
    }
    __syncthreads();
    int wave = threadIdx.x >> 6, lane = threadIdx.x & 63;
    for (int grp = 0; grp < 4; ++grp) {
        int s = s0 + wave * 8 + grp * 2;
        float acc[16][2];
        #pragma unroll
        for (int h = 0; h < 16; ++h) { acc[h][0] = 0.f; acc[h][1] = 0.f; }
        const float4* x0p = reinterpret_cast<const float4*>(tgt + ((long)b * SS + s) * DD + eh * EH);
        const float4* x1p = reinterpret_cast<const float4*>(tgt + ((long)b * SS + s + 1) * DD + eh * EH);
        const float4* p0p = reinterpret_cast<const float4*>(pe + (long)s * DD + eh * EH);
        const float4* p1p = reinterpret_cast<const float4*>(pe + (long)(s + 1) * DD + eh * EH);
        #pragma unroll
        for (int kb = 0; kb < 2; ++kb) {
            int j = kb * 64 + lane;
            float4 t0 = x0p[j], q0 = p0p[j];
            float4 x0v = make_float4(t0.x + q0.x, t0.y + q0.y, t0.z + q0.z, t0.w + q0.w);
            float4 t1 = x1p[j], q1 = p1p[j];
            float4 x1v = make_float4(t1.x + q1.x, t1.y + q1.y, t1.z + q1.z, t1.w + q1.w);
            #pragma unroll
            for (int h = 0; h < 16; ++h) {
                float4 uv = us4[h * 128 + j];
                acc[h][0] += uv.x * x0v.x + uv.y * x0v.y + uv.z * x0v.z + uv.w * x0v.w;
                acc[h][1] += uv.x * x1v.x + uv.y * x1v.y + uv.z * x1v.z + uv.w * x1v.w;
            }
        }
        #pragma unroll
        for (int h = 0; h < 16; ++h)
            #pragma unroll
            for (int r = 0; r < 2; ++r) {
                float v = acc[h][r];
                for (int off = 32; off; off >>= 1) v += __shfl_xor(v, off, 64);
                if (lane == 0)
                    scp[((long)eh * BB * HH + b * HH + h) * SS + s + r] = v;
            }
    }
}

// ---------------- softmax: combine halves, scale, softmax over 4096; write probabilities ----------------
__global__ __launch_bounds__(256) void softmax2_kernel(const float* __restrict__ scp,
                                                       float* __restrict__ sc)
{
    int row = blockIdx.x;   // b*H+h
    int t = threadIdx.x;
    const float4* p0 = reinterpret_cast<const float4*>(scp + (long)row * SS);
    const float4* p1 = reinterpret_cast<const float4*>(scp + ((long)BB * HH + row) * SS);
    float4 v[4];
    float mx = -1e30f;
    #pragma unroll
    for (int i = 0; i < 4; ++i) {
        float4 a = p0[t + 256 * i], bqq = p1[t + 256 * i];
        v[i] = make_float4((a.x + bqq.x) * 0.125f, (a.y + bqq.y) * 0.125f,
                           (a.z + bqq.z) * 0.125f, (a.w + bqq.w) * 0.125f);
        mx = fmaxf(mx, fmaxf(fmaxf(v[i].x, v[i].y), fmaxf(v[i].z, v[i].w)));
    }
    __shared__ float red[4];
    for (int off = 32; off; off >>= 1) mx = fmaxf(mx, __shfl_xor(mx, off, 64));
    if ((t & 63) == 0) red[t >> 6] = mx;
    __syncthreads();
    mx = fmaxf(fmaxf(red[0], red[1]), fmaxf(red[2], red[3]));
    __syncthreads();
    float sum = 0.f;
    #pragma unroll
    for (int i = 0; i < 4; ++i) {
        v[i].x = expf(v[i].x - mx); v[i].y = expf(v[i].y - mx);
        v[i].z = expf(v[i].z - mx); v[i].w = expf(v[i].w - mx);
        sum += v[i].x + v[i].y + v[i].z + v[i].w;
    }
    for (int off = 32; off; off >>= 1) sum += __shfl_xor(sum, off, 64);
    if ((t & 63) == 0) red[t >> 6] = sum;
    __syncthreads();
    sum = red[0] + red[1] + red[2] + red[3];
    float inv = 1.f / sum;
    float4* pw = reinterpret_cast<float4*>(sc + (long)row * SS);
    #pragma unroll
    for (int i = 0; i < 4; ++i) {
        v[i].x *= inv; v[i].y *= inv; v[i].z *= inv; v[i].w *= inv;
        pw[t + 256 * i] = v[i];
    }
}

// ---------------- ctx accumulate: ctx[b,h,e] += sum_{s in chunk} p[b,h,s]*x[b,s,e] ----------------
// grid (CTX_SC, BB), block 256; thread owns float4 e-strip of full D; p loads are wave-uniform (scalar cache).
__global__ __launch_bounds__(256) void ctx2_kernel(const float* __restrict__ tgt,
                                                   const float* __restrict__ pe,
                                                   const float* __restrict__ sc,
                                                   float* __restrict__ ctx)
{
    int c = blockIdx.x, b = blockIdx.y;
    int s0 = c * (SS / CTX_SC);
    int e = threadIdx.x * 4;
    float acc[16][4];
    #pragma unroll
    for (int h = 0; h < 16; ++h)
        #pragma unroll
        for (int r = 0; r < 4; ++r) acc[h][r] = 0.f;
    for (int sg = 0; sg < SS / CTX_SC; sg += 4) {
        float4 x[4];
        #pragma unroll
        for (int r = 0; r < 4; ++r) {
            int s = s0 + sg + r;
            float4 tv = *reinterpret_cast<const float4*>(tgt + ((long)b * SS + s) * DD + e);
            float4 pv = *reinterpret_cast<const float4*>(pe + (long)s * DD + e);
            x[r] = make_float4(tv.x + pv.x, tv.y + pv.y, tv.z + pv.z, tv.w + pv.w);
        }
        #pragma unroll
        for (int h = 0; h < 16; ++h) {
            float4 pv = *reinterpret_cast<const float4*>(sc + ((long)(b * HH + h)) * SS + s0 + sg);
            acc[h][0] += pv.x * x[0].x + pv.y * x[1].x + pv.z * x[2].x + pv.w * x[3].x;
            acc[h][1] += pv.x * x[0].y + pv.y * x[1].y + pv.z * x[2].y + pv.w * x[3].y;
            acc[h][2] += pv.x * x[0].z + pv.y * x[1].z + pv.z * x[2].z + pv.w * x[3].z;
            acc[h][3] += pv.x * x[0].w + pv.y * x[1].w + pv.z * x[2].w + pv.w * x[3].w;
        }
    }
    #pragma unroll
    for (int h = 0; h < 16; ++h)
        #pragma unroll
        for (int r = 0; r < 4; ++r)
            atomicAdd(&ctx[((long)(b * HH + h)) * DD + e + r], acc[h][r]);
}

// ---------------- o[b, j] = sum_e wv[j,e]*ctx[b, j>>6, e] + bv[j] ----------------
__global__ __launch_bounds__(256) void ov_kernel(const float* __restrict__ ctx,
                                                 const float* __restrict__ wv,
                                                 const float* __restrict__ bv,
                                                 float* __restrict__ o)
{
    int wave = threadIdx.x >> 6, lane = threadIdx.x & 63;
    int j = blockIdx.x * 4 + wave;
    if (j >= DD) return;
    int h = j >> 6;
    float acc[8] = {0.f,0.f,0.f,0.f,0.f,0.f,0.f,0.f};
    const float4* w4 = reinterpret_cast<const float4*>(wv + (long)j * DD);
    for (int kb = 0; kb < DD; kb += 256) {
        int k4 = (kb >> 2) + lane;
        float4 w = w4[k4];
        #pragma unroll
        for (int b = 0; b < 8; ++b) {
            float4 a = reinterpret_cast<const float4*>(ctx + ((long)(b * HH + h)) * DD)[k4];
            acc[b] += a.x * w.x + a.y * w.y + a.z * w.z + a.w * w.w;
        }
    }
    #pragma unroll
    for (int b = 0; b < 8; ++b)
        for (int off = 32; off; off >>= 1) acc[b] += __shfl_xor(acc[b], off, 64);
    if (lane == 0) {
        float bs = bv[j];
        #pragma unroll
        for (int b = 0; b < 8; ++b) o[(long)b * DD + j] = acc[b] + bs;
    }
}

extern "C" void kernel_launch(void* const* d_in, const int* in_sizes, int n_in,
                              void* d_out, int out_size, void* d_ws, size_t ws_size,
                              hipStream_t stream)
{
    const float* tgt        = (const float*)d_in[0];
    const float* in_proj_w  = (const float*)d_in[1];
    const float* in_proj_b  = (const float*)d_in[2];
    const float* out_proj_w = (const float*)d_in[3];
    const float* out_proj_b = (const float*)d_in[4];
    const float* ln1_w      = (const float*)d_in[5];
    const float* ln1_b      = (const float*)d_in[6];
    const float* lin1_w     = (const float*)d_in[7];
    const float* lin1_b     = (const float*)d_in[8];
    const float* lin2_w     = (const float*)d_in[9];
    const float* lin2_b     = (const float*)d_in[10];
    const float* ln2_w      = (const float*)d_in[11];
    const float* ln2_b      = (const float*)d_in[12];
    const float* w_out      = (const float*)d_in[13];
    const float* b_out      = (const float*)d_in[14];

    float* ws   = (float*)d_ws;
    float* pe   = ws + OFF_PE;
    float* scp  = ws + OFF_SCP;
    float* sc   = ws + OFF_SC;
    float* u    = ws + OFF_U;
    float* ctx  = ws + OFF_CTX;
    float* Q    = ws + OFF_Q;
    float* o    = ws + OFF_O;
    float* x0   = ws + OFF_X0;
    float* vb   = ws + OFF_V;
    float* o2   = ws + OFF_O2;
    float* y    = ws + OFF_Y;
    float* hb   = ws + OFF_H;
    float* z    = ws + OFF_Z;

    const float* tgt_last = tgt + (long)(SS - 1) * DD;
    const float* pe_last  = pe + (long)(SS - 1) * DD;

    // 1. positional encoding table
    pe_kernel<<<SS, 256, 0, stream>>>(pe);

    // 2. Q = (tgt_last + pe_last) @ wq0^T + bq0
    gemm8<<<DD / 4, 256, 0, stream>>>(tgt_last, (long)SS * DD, pe_last, 0L,
                                      in_proj_w, in_proj_b,
                                      nullptr, 0L, nullptr, 0L, Q, DD, DD, 0);

    // 3. u[b,h,:] = sum_d Q[b,h,d] * wk0[h*64+d,:]   (bk dropped: softmax-invariant)
    u_kernel<<<dim3(4, 16), 256, 0, stream>>>(Q, in_proj_w + (long)DD * DD, u);

    // 4. score partials (e-split), 5. combine+softmax, 6. ctx (atomic accumulate)
    score2_kernel<<<dim3(SS / 32, 2, BB), 256, 0, stream>>>(tgt, pe, u, scp);
    softmax2_kernel<<<BB * HH, 256, 0, stream>>>(scp, sc);
    hipMemsetAsync(ctx, 0, (size_t)BB * HH * DD * sizeof(float), stream);
    ctx2_kernel<<<dim3(CTX_SC, BB), 256, 0, stream>>>(tgt, pe, sc, ctx);

    // 7. o[b,:] = wv0 @ ctx + bv0   (sum a = 1 passes bias through)
    ov_kernel<<<DD / 4, 256, 0, stream>>>(ctx, in_proj_w + 2L * DD * DD, in_proj_b + 2 * DD, o);

    // 8. layer-0 tail
    gemm8<<<DD / 4, 256, 0, stream>>>(o, (long)DD, nullptr, 0L,
                                      out_proj_w, out_proj_b,
                                      tgt_last, (long)SS * DD, pe_last, 0L, o2, DD, DD, 0);
    ln8<<<BB, 256, 0, stream>>>(o2, ln1_w, ln1_b, y, DD);
    gemm8<<<FF / 4, 256, 0, stream>>>(y, (long)DD, nullptr, 0L,
                                      lin1_w, lin1_b,
                                      nullptr, 0L, nullptr, 0L, hb, FF, DD, 1);
    gemm8<<<DD / 4, 256, 0, stream>>>(hb, (long)FF, nullptr, 0L,
                                      lin2_w, lin2_b,
                                      y, (long)DD, nullptr, 0L, z, DD, FF, 0);
    ln8<<<BB, 256, 0, stream>>>(z, ln2_w, ln2_b, x0, DD);

    // 9. layers 1..5: seq len 1 -> softmax(1)=1 -> attn out = x0 @ wv^T + bv
    for (int i = 1; i < LL; ++i) {
        const float* wv_i = in_proj_w + (long)i * 3 * DD * DD + 2L * DD * DD;
        const float* bv_i = in_proj_b + (long)i * 3 * DD + 2 * DD;
        gemm8<<<DD / 4, 256, 0, stream>>>(x0, (long)DD, nullptr, 0L,
                                          wv_i, bv_i, nullptr, 0L, nullptr, 0L, vb, DD, DD, 0);
        gemm8<<<DD / 4, 256, 0, stream>>>(vb, (long)DD, nullptr, 0L,
                                          out_proj_w + (long)i * DD * DD, out_proj_b + (long)i * DD,
                                          x0, (long)DD, nullptr, 0L, o2, DD, DD, 0);
        ln8<<<BB, 256, 0, stream>>>(o2, ln1_w + (long)i * DD, ln1_b + (long)i * DD, y, DD);
        gemm8<<<FF / 4, 256, 0, stream>>>(y, (long)DD, nullptr, 0L,
                                          lin1_w + (long)i * FF * DD, lin1_b + (long)i * FF,
                                          nullptr, 0L, nullptr, 0L, hb, FF, DD, 1);
        gemm8<<<DD / 4, 256, 0, stream>>>(hb, (long)FF, nullptr, 0L,
                                          lin2_w + (long)i * DD * FF, lin2_b + (long)i * DD,
                                          y, (long)DD, nullptr, 0L, z, DD, FF, 0);
        ln8<<<BB, 256, 0, stream>>>(z, ln2_w + (long)i * DD, ln2_b + (long)i * DD, x0, DD);
    }

    // 10. final projection -> (B, 256)
    gemm8<<<VV / 4, 256, 0, stream>>>(x0, (long)DD, nullptr, 0L,
                                      w_out, b_out,
                                      nullptr, 0L, nullptr, 0L, (float*)d_out, VV, DD, 0);
}